// Round 1
// baseline (747.479 us; speedup 1.0000x reference)
//
#include <hip/hip_runtime.h>
#include <math.h>

#define THREADS 256
#define KC 32
#define APAD 4   // As row stride = KC+APAD = 36 floats (keeps float4 alignment, breaks bank aliasing)

__device__ __forceinline__ float clipf(float v){ return fminf(fmaxf(v, -10.f), 10.f); }

// ---------------------------------------------------------------- CSR build
__global__ __launch_bounds__(256) void count_deg(const int* dstv, int E, int* deg){
    int i = blockIdx.x*256 + threadIdx.x;
    if (i < E) atomicAdd(&deg[dstv[i]], 1);
}

#define SCAN_CHUNK 1024
__global__ __launch_bounds__(256) void scan1(const int* deg, int N, int* row_start, int* chunksum){
    __shared__ int sh[256];
    int b = blockIdx.x, t = threadIdx.x;
    int base = b*SCAN_CHUNK + t*4;
    int d0 = (base+0 < N) ? deg[base+0] : 0;
    int d1 = (base+1 < N) ? deg[base+1] : 0;
    int d2 = (base+2 < N) ? deg[base+2] : 0;
    int d3 = (base+3 < N) ? deg[base+3] : 0;
    int ts = d0+d1+d2+d3;
    sh[t] = ts; __syncthreads();
    for (int off = 1; off < 256; off <<= 1){
        int v = (t >= off) ? sh[t-off] : 0;
        __syncthreads();
        sh[t] += v;
        __syncthreads();
    }
    int ex = sh[t] - ts;
    if (base+0 < N) row_start[base+0] = ex;
    if (base+1 < N) row_start[base+1] = ex + d0;
    if (base+2 < N) row_start[base+2] = ex + d0 + d1;
    if (base+3 < N) row_start[base+3] = ex + d0 + d1 + d2;
    if (t == 255) chunksum[b] = sh[255];
}

// valid for nb <= 256 (N=100000 -> nb=98)
__global__ __launch_bounds__(256) void scan2(int* chunksum, int nb){
    __shared__ int sh[256];
    int t = threadIdx.x;
    int v = (t < nb) ? chunksum[t] : 0;
    sh[t] = v; __syncthreads();
    for (int off = 1; off < 256; off <<= 1){
        int u = (t >= off) ? sh[t-off] : 0;
        __syncthreads();
        sh[t] += u;
        __syncthreads();
    }
    if (t < nb) chunksum[t] = sh[t] - v;   // exclusive
}

__global__ __launch_bounds__(256) void scan3(int* row_start, const int* chunksum, int N, int E){
    int i = blockIdx.x*256 + threadIdx.x;
    if (i < N) row_start[i] += chunksum[i >> 10];
    if (i == 0) row_start[N] = E;
}

__global__ __launch_bounds__(256) void fill_csr(const int* srcv, const int* dstv, int E,
                                                const int* row_start, int* cursor, int* col_idx){
    int i = blockIdx.x*256 + threadIdx.x;
    if (i < E){
        int d = dstv[i];
        int pos = atomicAdd(&cursor[d], 1);
        col_idx[row_start[d] + pos] = srcv[i];
    }
}

__global__ __launch_bounds__(256) void flag_users(const int* uid, int B, int* flag){
    int i = blockIdx.x*256 + threadIdx.x;
    if (i < B) flag[uid[i]] = 1;
}

// ---------------------------------------------------------------- weight prep
// out[k*outN + j] = in[j*K + k]   (j < R rows of in, k < K cols of in)
__global__ __launch_bounds__(256) void transpose_k(const float* in, float* out, int R, int K, int outN){
    int idx = blockIdx.x*256 + threadIdx.x;
    if (idx >= R*K) return;
    int j = idx / K, k = idx % K;
    out[k*outN + j] = in[j*K + k];
}

// gates weights: jj in [0,384) maps to w_ih row j (i:0-127, g:256-383, o:384-511); f-gate is dead (c0=0).
__global__ __launch_bounds__(256) void prep_gates(const float* w_ih, const float* b_ih, const float* b_hh,
                                                  float* wtg, float* bsum, float* ohtab){
    int idx = blockIdx.x*256 + threadIdx.x;
    if (idx < 256*384){
        int jj = idx % 384, k = idx / 384;
        int j = jj + ((jj >= 128) ? 128 : 0);
        wtg[k*384 + jj] = w_ih[j*261 + k];
    }
    if (idx < 384){
        int jj = idx; int j = jj + ((jj >= 128) ? 128 : 0);
        bsum[jj] = b_ih[j] + b_hh[j];
        for (int r = 0; r < 5; ++r) ohtab[r*384 + jj] = w_ih[j*261 + 256 + r];
    }
}

// ---------------------------------------------------------------- mean aggregation (CSR gather)
// one 64-lane wave per node, 2 floats per lane; if flag!=null only flagged nodes computed
__global__ __launch_bounds__(256) void aggregate_k(const float* feat, const int* row_start,
                                                   const int* col_idx, const int* flag,
                                                   float* outmean, int N){
    int wave = (blockIdx.x*256 + threadIdx.x) >> 6;
    int lane = threadIdx.x & 63;
    if (wave >= N) return;
    if (flag && !flag[wave]) return;
    int s = row_start[wave], e = row_start[wave+1];
    float2 acc = make_float2(0.f, 0.f);
    for (int i = s; i < e; ++i){
        int src = col_idx[i];
        float2 v = *(const float2*)(feat + (long)src*128 + lane*2);
        acc.x += v.x; acc.y += v.y;
    }
    float inv = 1.f / fmaxf((float)(e - s), 1.f);
    acc.x *= inv; acc.y *= inv;
    *(float2*)(outmean + (long)wave*128 + lane*2) = acc;
}

// ---------------------------------------------------------------- generic fp32 GEMM
// MODE 0: h    = relu([mean0|x]      @ wt0 + b_l0)           M=N rows
// MODE 1: ue   = clip([mean1|h][uid] @ wt1 + b_l1)           M=B rows (gathered)
// MODE 2: gates=      [ue|clip(x[uid])] @ wtg + bsum + onehot M=B rows
// MODE 3: z0   = relu([ue|lstm]      @ wtc0 + bc0)
// MODE 4: z1   = relu(z0             @ wtc1 + bc1)  (K=128, BN=64)
struct GemmArgs {
    const float* a0; const float* a1; const int* g;
    const float* wt; int ncolsW;
    const float* bias; const float* ohtab; const int* roles;
    float* out; int ncolsOut; int M;
};

template<int MODE>
__device__ __forceinline__ float4 load_a(const GemmArgs& A, int row, int k){
    if constexpr (MODE == 1){
        int node = A.g[row];
        const float* p = (k < 128) ? A.a0 + (long)node*128 + k : A.a1 + (long)node*128 + (k-128);
        return *(const float4*)p;
    } else if constexpr (MODE == 2){
        if (k < 128) return *(const float4*)(A.a0 + (long)row*128 + k);
        int node = A.g[row];
        float4 v = *(const float4*)(A.a1 + (long)node*128 + (k-128));
        v.x = clipf(v.x); v.y = clipf(v.y); v.z = clipf(v.z); v.w = clipf(v.w);
        return v;
    } else if constexpr (MODE == 4){
        return *(const float4*)(A.a0 + (long)row*128 + k);
    } else {
        const float* p = (k < 128) ? A.a0 + (long)row*128 + k : A.a1 + (long)row*128 + (k-128);
        return *(const float4*)p;
    }
}

template<int MODE>
__global__ __launch_bounds__(THREADS) void gemm_k(GemmArgs A){
    constexpr int BM = 64;
    constexpr int BN = (MODE == 4) ? 64 : 128;
    constexpr int TN = 4;
    constexpr int CT = BN / TN;          // col-threads: 32 or 16
    constexpr int RT = THREADS / CT;     // row-threads: 8 or 16
    constexpr int TM = BM / RT;          // 8 or 4
    constexpr int KTOT = (MODE == 4) ? 128 : 256;

    __shared__ __align__(16) float As[BM][KC + APAD];
    __shared__ __align__(16) float Ws[KC][BN];

    const int tid  = threadIdx.x;
    const int row0 = blockIdx.x * BM;
    const int col0 = blockIdx.y * BN;
    const int c  = tid % CT;
    const int rt = tid / CT;

    float acc[TM][TN];
    #pragma unroll
    for (int i = 0; i < TM; ++i)
        #pragma unroll
        for (int j = 0; j < TN; ++j) acc[i][j] = 0.f;

    for (int ko = 0; ko < KTOT; ko += KC){
        #pragma unroll
        for (int it = 0; it < (BM*KC/4)/THREADS; ++it){      // 2 iters
            int idx = it*THREADS + tid;
            int r  = idx >> 3;         // KC/4 = 8 float4 per row
            int k4 = idx & 7;
            int grow = row0 + r; if (grow >= A.M) grow = A.M - 1;
            float4 v = load_a<MODE>(A, grow, ko + k4*4);
            *(float4*)&As[r][k4*4] = v;
        }
        #pragma unroll
        for (int it = 0; it < (KC*BN/4)/THREADS; ++it){      // 4 (BN=128) or 2 (BN=64)
            int idx = it*THREADS + tid;
            int kk = idx / (BN/4);
            int c4 = idx % (BN/4);
            float4 v = *(const float4*)&A.wt[(long)(ko+kk)*A.ncolsW + col0 + c4*4];
            *(float4*)&Ws[kk][c4*4] = v;
        }
        __syncthreads();
        #pragma unroll
        for (int kk = 0; kk < KC; ++kk){
            float4 wv = *(const float4*)&Ws[kk][c*4];
            float w[TN] = {wv.x, wv.y, wv.z, wv.w};
            float a[TM];
            #pragma unroll
            for (int i = 0; i < TM; ++i) a[i] = As[rt*TM + i][kk];
            #pragma unroll
            for (int i = 0; i < TM; ++i)
                #pragma unroll
                for (int j = 0; j < TN; ++j) acc[i][j] = fmaf(a[i], w[j], acc[i][j]);
        }
        __syncthreads();
    }

    #pragma unroll
    for (int i = 0; i < TM; ++i){
        int grow = row0 + rt*TM + i;
        if (grow >= A.M) continue;
        #pragma unroll
        for (int j = 0; j < TN; ++j){
            int gcol = col0 + c*4 + j;
            float v = acc[i][j];
            if constexpr (MODE == 0)      v = fmaxf(v + A.bias[gcol], 0.f);
            else if constexpr (MODE == 1) v = clipf(v + A.bias[gcol]);
            else if constexpr (MODE == 2) v = v + A.bias[gcol] + A.ohtab[A.roles[grow]*384 + gcol];
            else                          v = fmaxf(v + A.bias[gcol], 0.f);
            A.out[(long)grow*A.ncolsOut + gcol] = v;
        }
    }
}

// ---------------------------------------------------------------- LSTM activation (f-gate dead, c0=0)
__global__ __launch_bounds__(256) void lstm_act(const float* gates, float* lstm, int B){
    int idx = blockIdx.x*256 + threadIdx.x;
    if (idx >= B*128) return;
    int b = idx >> 7, j = idx & 127;
    const float* gr = gates + (long)b*384;
    float i_ = gr[j], g_ = gr[128 + j], o_ = gr[256 + j];
    float si = 1.f/(1.f + expf(-i_));
    float c  = si * tanhf(g_);
    float so = 1.f/(1.f + expf(-o_));
    lstm[idx] = clipf(so * tanhf(c));
}

// ---------------------------------------------------------------- final tiny GEMM [B,64]@[64,5]
__global__ __launch_bounds__(256) void out_k(const float* z1, const float* wc2, const float* bc2,
                                             float* out, int B){
    int idx = blockIdx.x*256 + threadIdx.x;
    int b = idx >> 3, r = idx & 7;
    if (b >= B || r >= 5) return;
    const float* zr = z1 + (long)b*64;
    const float* wr = wc2 + r*64;
    float acc = bc2[r];
    #pragma unroll 16
    for (int k = 0; k < 64; ++k) acc = fmaf(zr[k], wr[k], acc);
    out[b*5 + r] = acc;
}

// ----------------------------------------------------------------
extern "C" void kernel_launch(void* const* d_in, const int* in_sizes, int n_in,
                              void* d_out, int out_size, void* d_ws, size_t ws_size,
                              hipStream_t stream){
    const float* x     = (const float*)d_in[0];
    const int*   edge  = (const int*)  d_in[1];
    const int*   uid   = (const int*)  d_in[2];
    const int*   roles = (const int*)  d_in[3];
    const float* w_l0  = (const float*)d_in[4];
    const float* b_l0  = (const float*)d_in[5];
    const float* w_r0  = (const float*)d_in[6];
    const float* w_l1  = (const float*)d_in[7];
    const float* b_l1  = (const float*)d_in[8];
    const float* w_r1  = (const float*)d_in[9];
    const float* w_ih  = (const float*)d_in[10];
    // d_in[11] = w_hh: dead (h0 = 0)
    const float* b_ih  = (const float*)d_in[12];
    const float* b_hh  = (const float*)d_in[13];
    const float* wc0   = (const float*)d_in[14];
    const float* bc0   = (const float*)d_in[15];
    const float* wc1   = (const float*)d_in[16];
    const float* bc1   = (const float*)d_in[17];
    const float* wc2   = (const float*)d_in[18];
    const float* bc2   = (const float*)d_in[19];

    const int N = in_sizes[0] / 128;
    const int E = in_sizes[1] / 2;
    const int B = in_sizes[2];

    char* ws = (char*)d_ws;
    size_t off = 0;
    auto alloc = [&](size_t bytes) -> void* {
        void* p = ws + off; off += (bytes + 255) & ~(size_t)255; return p;
    };
    float* arenaA   = (float*)alloc((size_t)N*128*4);   // mean0 -> mean1 -> gates
    float* arenaB   = (float*)alloc((size_t)N*128*4);   // h -> lstm/z0/z1
    float* ue       = (float*)alloc((size_t)B*128*4);
    int*   degi     = (int*)  alloc((size_t)N*4);
    int*   cursor   = (int*)  alloc((size_t)N*4);
    int*   flag     = (int*)  alloc((size_t)N*4);
    int*   row_start= (int*)  alloc((size_t)(N+1)*4);
    int*   chunksum = (int*)  alloc(1024*4);
    int*   col_idx  = (int*)  alloc((size_t)E*4);
    float* wt0      = (float*)alloc(256*128*4);
    float* wt1      = (float*)alloc(256*128*4);
    float* wtg      = (float*)alloc(256*384*4);
    float* bsum     = (float*)alloc(384*4);
    float* ohtab    = (float*)alloc(5*384*4);
    float* wtc0     = (float*)alloc(256*128*4);
    float* wtc1     = (float*)alloc(128*64*4);

    float* mean0 = arenaA;
    float* h     = arenaB;
    float* mean1 = arenaA;                       // mean0 consumed by gemm<0> before this
    float* gates = arenaA;                       // mean1 consumed by gemm<1> before this
    float* lstm  = arenaB;                       // h consumed by gemm<1> before this
    float* z0    = arenaB + (size_t)B*128;
    float* z1    = arenaB + (size_t)B*128*2;

    hipMemsetAsync(degi,   0, (size_t)N*4, stream);
    hipMemsetAsync(cursor, 0, (size_t)N*4, stream);
    hipMemsetAsync(flag,   0, (size_t)N*4, stream);

    const int gE = (E + 255)/256;
    const int nchunk = (N + SCAN_CHUNK - 1)/SCAN_CHUNK;

    count_deg<<<gE, 256, 0, stream>>>(edge + E, E, degi);
    scan1<<<nchunk, 256, 0, stream>>>(degi, N, row_start, chunksum);
    scan2<<<1, 256, 0, stream>>>(chunksum, nchunk);
    scan3<<<(N + 255)/256, 256, 0, stream>>>(row_start, chunksum, N, E);
    fill_csr<<<gE, 256, 0, stream>>>(edge, edge + E, E, row_start, cursor, col_idx);
    flag_users<<<(B + 255)/256, 256, 0, stream>>>(uid, B, flag);

    transpose_k<<<(128*128 + 255)/256, 256, 0, stream>>>(w_l0, wt0,            128, 128, 128);
    transpose_k<<<(128*128 + 255)/256, 256, 0, stream>>>(w_r0, wt0 + 128*128,  128, 128, 128);
    transpose_k<<<(128*128 + 255)/256, 256, 0, stream>>>(w_l1, wt1,            128, 128, 128);
    transpose_k<<<(128*128 + 255)/256, 256, 0, stream>>>(w_r1, wt1 + 128*128,  128, 128, 128);
    transpose_k<<<(128*256 + 255)/256, 256, 0, stream>>>(wc0,  wtc0,           128, 256, 128);
    transpose_k<<<( 64*128 + 255)/256, 256, 0, stream>>>(wc1,  wtc1,            64, 128,  64);
    prep_gates<<<(256*384 + 255)/256, 256, 0, stream>>>(w_ih, b_ih, b_hh, wtg, bsum, ohtab);

    // layer 0: mean over all nodes, then h = relu([mean0|x] @ [w_l0|w_r0]^T + b_l0)
    aggregate_k<<<(N + 3)/4, 256, 0, stream>>>(x, row_start, col_idx, nullptr, mean0, N);
    GemmArgs gh { mean0, x, nullptr, wt0, 128, b_l0, nullptr, nullptr, h, 128, N };
    gemm_k<0><<<dim3((N + 63)/64, 1), THREADS, 0, stream>>>(gh);

    // layer 1: aggregation + dense only for user nodes
    aggregate_k<<<(N + 3)/4, 256, 0, stream>>>(h, row_start, col_idx, flag, mean1, N);
    GemmArgs gu { mean1, h, uid, wt1, 128, b_l1, nullptr, nullptr, ue, 128, B };
    gemm_k<1><<<dim3(B/64, 1), THREADS, 0, stream>>>(gu);

    // LSTM gates (i,g,o only) + activation
    GemmArgs gg { ue, x, uid, wtg, 384, bsum, ohtab, roles, gates, 384, B };
    gemm_k<2><<<dim3(B/64, 3), THREADS, 0, stream>>>(gg);
    lstm_act<<<(B*128 + 255)/256, 256, 0, stream>>>(gates, lstm, B);

    // classifier MLP
    GemmArgs gz0 { ue, lstm, nullptr, wtc0, 128, bc0, nullptr, nullptr, z0, 128, B };
    gemm_k<3><<<dim3(B/64, 1), THREADS, 0, stream>>>(gz0);
    GemmArgs gz1 { z0, nullptr, nullptr, wtc1, 64, bc1, nullptr, nullptr, z1, 64, B };
    gemm_k<4><<<dim3(B/64, 1), THREADS, 0, stream>>>(gz1);
    out_k<<<(B*8 + 255)/256, 256, 0, stream>>>(z1, wc2, bc2, (float*)d_out, B);

    (void)n_in; (void)out_size; (void)ws_size;
}

// Round 2
// 687.630 us; speedup vs baseline: 1.0870x; 1.0870x over previous
//
#include <hip/hip_runtime.h>
#include <math.h>

#define THREADS 256
#define KC 32

__device__ __forceinline__ float clipf(float v){ return fminf(fmaxf(v, -10.f), 10.f); }

// ---------------------------------------------------------------- CSR build
__global__ __launch_bounds__(256) void count_deg(const int* __restrict__ dstv, int E, int* __restrict__ deg){
    int i = blockIdx.x*256 + threadIdx.x;
    if (i < E) atomicAdd(&deg[dstv[i]], 1);
}

#define SCAN_CHUNK 1024
__global__ __launch_bounds__(256) void scan1(const int* __restrict__ deg, int N, int* __restrict__ row_start, int* __restrict__ chunksum){
    __shared__ int sh[256];
    int b = blockIdx.x, t = threadIdx.x;
    int base = b*SCAN_CHUNK + t*4;
    int d0 = (base+0 < N) ? deg[base+0] : 0;
    int d1 = (base+1 < N) ? deg[base+1] : 0;
    int d2 = (base+2 < N) ? deg[base+2] : 0;
    int d3 = (base+3 < N) ? deg[base+3] : 0;
    int ts = d0+d1+d2+d3;
    sh[t] = ts; __syncthreads();
    for (int off = 1; off < 256; off <<= 1){
        int v = (t >= off) ? sh[t-off] : 0;
        __syncthreads();
        sh[t] += v;
        __syncthreads();
    }
    int ex = sh[t] - ts;
    if (base+0 < N) row_start[base+0] = ex;
    if (base+1 < N) row_start[base+1] = ex + d0;
    if (base+2 < N) row_start[base+2] = ex + d0 + d1;
    if (base+3 < N) row_start[base+3] = ex + d0 + d1 + d2;
    if (t == 255) chunksum[b] = sh[255];
}

// valid for nb <= 256 (N=100000 -> nb=98)
__global__ __launch_bounds__(256) void scan2(int* __restrict__ chunksum, int nb){
    __shared__ int sh[256];
    int t = threadIdx.x;
    int v = (t < nb) ? chunksum[t] : 0;
    sh[t] = v; __syncthreads();
    for (int off = 1; off < 256; off <<= 1){
        int u = (t >= off) ? sh[t-off] : 0;
        __syncthreads();
        sh[t] += u;
        __syncthreads();
    }
    if (t < nb) chunksum[t] = sh[t] - v;   // exclusive
}

__global__ __launch_bounds__(256) void scan3(int* __restrict__ row_start, const int* __restrict__ chunksum, int N, int E){
    int i = blockIdx.x*256 + threadIdx.x;
    if (i < N) row_start[i] += chunksum[i >> 10];
    if (i == 0) row_start[N] = E;
}

__global__ __launch_bounds__(256) void fill_csr(const int* __restrict__ srcv, const int* __restrict__ dstv, int E,
                                                const int* __restrict__ row_start, int* __restrict__ cursor, int* __restrict__ col_idx){
    int i = blockIdx.x*256 + threadIdx.x;
    if (i < E){
        int d = dstv[i];
        int pos = atomicAdd(&cursor[d], 1);
        col_idx[row_start[d] + pos] = srcv[i];
    }
}

__global__ __launch_bounds__(256) void flag_users(const int* __restrict__ uid, int B, int* __restrict__ flag){
    int i = blockIdx.x*256 + threadIdx.x;
    if (i < B) flag[uid[i]] = 1;
}

__global__ __launch_bounds__(256) void compact_flags(const int* __restrict__ flag, int N, int* __restrict__ list, int* __restrict__ cnt){
    int i = blockIdx.x*256 + threadIdx.x;
    if (i < N && flag[i]){ int p = atomicAdd(cnt, 1); list[p] = i; }
}

// ---------------------------------------------------------------- weight prep
__global__ __launch_bounds__(256) void transpose_k(const float* __restrict__ in, float* __restrict__ out, int R, int K, int outN){
    int idx = blockIdx.x*256 + threadIdx.x;
    if (idx >= R*K) return;
    int j = idx / K, k = idx % K;
    out[k*outN + j] = in[j*K + k];
}

// gates weights: jj in [0,384) maps to w_ih row j (i:0-127, g:256-383, o:384-511); f-gate dead (c0=0).
__global__ __launch_bounds__(256) void prep_gates(const float* __restrict__ w_ih, const float* __restrict__ b_ih, const float* __restrict__ b_hh,
                                                  float* __restrict__ wtg, float* __restrict__ bsum, float* __restrict__ ohtab){
    int idx = blockIdx.x*256 + threadIdx.x;
    if (idx < 256*384){
        int jj = idx % 384, k = idx / 384;
        int j = jj + ((jj >= 128) ? 128 : 0);
        wtg[k*384 + jj] = w_ih[j*261 + k];
    }
    if (idx < 384){
        int jj = idx; int j = jj + ((jj >= 128) ? 128 : 0);
        bsum[jj] = b_ih[j] + b_hh[j];
        for (int r = 0; r < 5; ++r) ohtab[r*384 + jj] = w_ih[j*261 + 256 + r];
    }
}

// ---------------------------------------------------------------- mean aggregation (CSR gather)
// one 64-lane wave per node; lanes split into 2 halves of 32, each half handles alternate
// edges with float4 (16B) loads; 2x manual unroll => 4 independent gathers in flight.
__global__ __launch_bounds__(256) void aggregate_k(const float* __restrict__ feat, const int* __restrict__ row_start,
                                                   const int* __restrict__ col_idx,
                                                   const int* __restrict__ list, const int* __restrict__ cnt,
                                                   float* __restrict__ outmean, int N){
    int wave = (blockIdx.x*256 + threadIdx.x) >> 6;
    int lane = threadIdx.x & 63;
    int node;
    if (list){
        if (wave >= *cnt) return;
        node = list[wave];
    } else {
        if (wave >= N) return;
        node = wave;
    }
    int s = row_start[node], e = row_start[node+1];
    int half = lane >> 5;       // 0/1: alternate edges
    int sl   = lane & 31;       // float4 slot within the 128-float row
    const float4* feat4 = (const float4*)feat;
    float4 a0 = make_float4(0.f,0.f,0.f,0.f);
    float4 a1 = make_float4(0.f,0.f,0.f,0.f);
    int i = s + half;
    for (; i + 6 < e; i += 8){
        int s0 = col_idx[i];
        int s1 = col_idx[i+2];
        int s2 = col_idx[i+4];
        int s3 = col_idx[i+6];
        float4 v0 = feat4[(long)s0*32 + sl];
        float4 v1 = feat4[(long)s1*32 + sl];
        float4 v2 = feat4[(long)s2*32 + sl];
        float4 v3 = feat4[(long)s3*32 + sl];
        a0.x += v0.x + v1.x; a0.y += v0.y + v1.y; a0.z += v0.z + v1.z; a0.w += v0.w + v1.w;
        a1.x += v2.x + v3.x; a1.y += v2.y + v3.y; a1.z += v2.z + v3.z; a1.w += v2.w + v3.w;
    }
    for (; i < e; i += 2){
        int s0 = col_idx[i];
        float4 v0 = feat4[(long)s0*32 + sl];
        a0.x += v0.x; a0.y += v0.y; a0.z += v0.z; a0.w += v0.w;
    }
    a0.x += a1.x; a0.y += a1.y; a0.z += a1.z; a0.w += a1.w;
    // combine the two halves (edge-parity partial sums)
    a0.x += __shfl_xor(a0.x, 32, 64);
    a0.y += __shfl_xor(a0.y, 32, 64);
    a0.z += __shfl_xor(a0.z, 32, 64);
    a0.w += __shfl_xor(a0.w, 32, 64);
    if (half == 0){
        float inv = 1.f / fmaxf((float)(e - s), 1.f);
        a0.x *= inv; a0.y *= inv; a0.z *= inv; a0.w *= inv;
        ((float4*)outmean)[(long)node*32 + sl] = a0;
    }
}

// ---------------------------------------------------------------- generic fp32 GEMM
// MODE 0: h    = relu([mean0|x]      @ wt0 + b_l0)            M=N rows
// MODE 1: ue   = clip([mean1|h][uid] @ wt1 + b_l1)            M=B rows (gathered)
// MODE 2: gates=      [ue|clip(x[uid])] @ wtg + bsum + onehot M=B rows
// MODE 3: z0   = relu([ue|lstm]      @ wtc0 + bc0)
// MODE 4: z1   = relu(z0             @ wtc1 + bc1)  (K=128, BN=64)
struct GemmArgs {
    const float* a0; const float* a1; const int* g;
    const float* wt; int ncolsW;
    const float* bias; const float* ohtab; const int* roles;
    float* out; int ncolsOut; int M;
};

template<int MODE>
__device__ __forceinline__ float4 load_a(const GemmArgs& A, int row, int k){
    if constexpr (MODE == 1){
        int node = A.g[row];
        const float* p = (k < 128) ? A.a0 + (long)node*128 + k : A.a1 + (long)node*128 + (k-128);
        return *(const float4*)p;
    } else if constexpr (MODE == 2){
        if (k < 128) return *(const float4*)(A.a0 + (long)row*128 + k);
        int node = A.g[row];
        float4 v = *(const float4*)(A.a1 + (long)node*128 + (k-128));
        v.x = clipf(v.x); v.y = clipf(v.y); v.z = clipf(v.z); v.w = clipf(v.w);
        return v;
    } else if constexpr (MODE == 4){
        return *(const float4*)(A.a0 + (long)row*128 + k);
    } else {
        const float* p = (k < 128) ? A.a0 + (long)row*128 + k : A.a1 + (long)row*128 + (k-128);
        return *(const float4*)p;
    }
}

template<int MODE>
__global__ __launch_bounds__(THREADS) void gemm_k(GemmArgs A){
    constexpr int BM = 64;
    constexpr int BN = (MODE == 4) ? 64 : 128;
    constexpr int TN = 4;
    constexpr int CT = BN / TN;          // col-threads: 32 or 16
    constexpr int RT = THREADS / CT;     // row-threads: 8 or 16
    constexpr int TM = BM / RT;          // 8 or 4
    constexpr int KTOT = (MODE == 4) ? 128 : 256;
    constexpr int AST = BM + 4;          // 68: rows stay 16B-aligned (68*4 = 272 = 17*16)

    // k-major A tile: inner-loop A reads become broadcast ds_read_b128
    __shared__ __align__(16) float As[KC][AST];
    __shared__ __align__(16) float Ws[KC][BN];

    const int tid  = threadIdx.x;
    const int row0 = blockIdx.x * BM;
    const int col0 = blockIdx.y * BN;
    const int c  = tid % CT;
    const int rt = tid / CT;

    float acc[TM][TN];
    #pragma unroll
    for (int i = 0; i < TM; ++i)
        #pragma unroll
        for (int j = 0; j < TN; ++j) acc[i][j] = 0.f;

    for (int ko = 0; ko < KTOT; ko += KC){
        #pragma unroll
        for (int it = 0; it < (BM*KC/4)/THREADS; ++it){      // 2 iters
            int idx = it*THREADS + tid;
            int r  = idx >> 3;         // KC/4 = 8 float4 per row
            int k4 = idx & 7;
            int grow = row0 + r; if (grow >= A.M) grow = A.M - 1;
            float4 v = load_a<MODE>(A, grow, ko + k4*4);
            As[k4*4+0][r] = v.x;
            As[k4*4+1][r] = v.y;
            As[k4*4+2][r] = v.z;
            As[k4*4+3][r] = v.w;
        }
        #pragma unroll
        for (int it = 0; it < (KC*BN/4)/THREADS; ++it){      // 4 (BN=128) or 2 (BN=64)
            int idx = it*THREADS + tid;
            int kk = idx / (BN/4);
            int c4 = idx % (BN/4);
            float4 v = *(const float4*)&A.wt[(long)(ko+kk)*A.ncolsW + col0 + c4*4];
            *(float4*)&Ws[kk][c4*4] = v;
        }
        __syncthreads();
        #pragma unroll
        for (int kk = 0; kk < KC; ++kk){
            float4 wv = *(const float4*)&Ws[kk][c*4];
            float w[TN] = {wv.x, wv.y, wv.z, wv.w};
            float a[TM];
            #pragma unroll
            for (int q = 0; q < TM/4; ++q){
                float4 av = *(const float4*)&As[kk][rt*TM + q*4];
                a[q*4+0] = av.x; a[q*4+1] = av.y; a[q*4+2] = av.z; a[q*4+3] = av.w;
            }
            #pragma unroll
            for (int i = 0; i < TM; ++i)
                #pragma unroll
                for (int j = 0; j < TN; ++j) acc[i][j] = fmaf(a[i], w[j], acc[i][j]);
        }
        __syncthreads();
    }

    #pragma unroll
    for (int i = 0; i < TM; ++i){
        int grow = row0 + rt*TM + i;
        if (grow >= A.M) continue;
        #pragma unroll
        for (int j = 0; j < TN; ++j){
            int gcol = col0 + c*4 + j;
            float v = acc[i][j];
            if constexpr (MODE == 0)      v = fmaxf(v + A.bias[gcol], 0.f);
            else if constexpr (MODE == 1) v = clipf(v + A.bias[gcol]);
            else if constexpr (MODE == 2) v = v + A.bias[gcol] + A.ohtab[A.roles[grow]*384 + gcol];
            else                          v = fmaxf(v + A.bias[gcol], 0.f);
            A.out[(long)grow*A.ncolsOut + gcol] = v;
        }
    }
}

// ---------------------------------------------------------------- LSTM activation (f-gate dead, c0=0)
__global__ __launch_bounds__(256) void lstm_act(const float* __restrict__ gates, float* __restrict__ lstm, int B){
    int idx = blockIdx.x*256 + threadIdx.x;
    if (idx >= B*128) return;
    int b = idx >> 7, j = idx & 127;
    const float* gr = gates + (long)b*384;
    float i_ = gr[j], g_ = gr[128 + j], o_ = gr[256 + j];
    float si = 1.f/(1.f + expf(-i_));
    float c  = si * tanhf(g_);
    float so = 1.f/(1.f + expf(-o_));
    lstm[idx] = clipf(so * tanhf(c));
}

// ---------------------------------------------------------------- final tiny GEMM [B,64]@[64,5]
__global__ __launch_bounds__(256) void out_k(const float* __restrict__ z1, const float* __restrict__ wc2, const float* __restrict__ bc2,
                                             float* __restrict__ out, int B){
    int idx = blockIdx.x*256 + threadIdx.x;
    int b = idx >> 3, r = idx & 7;
    if (b >= B || r >= 5) return;
    const float* zr = z1 + (long)b*64;
    const float* wr = wc2 + r*64;
    float acc = bc2[r];
    #pragma unroll 16
    for (int k = 0; k < 64; ++k) acc = fmaf(zr[k], wr[k], acc);
    out[b*5 + r] = acc;
}

// ----------------------------------------------------------------
extern "C" void kernel_launch(void* const* d_in, const int* in_sizes, int n_in,
                              void* d_out, int out_size, void* d_ws, size_t ws_size,
                              hipStream_t stream){
    const float* x     = (const float*)d_in[0];
    const int*   edge  = (const int*)  d_in[1];
    const int*   uid   = (const int*)  d_in[2];
    const int*   roles = (const int*)  d_in[3];
    const float* w_l0  = (const float*)d_in[4];
    const float* b_l0  = (const float*)d_in[5];
    const float* w_r0  = (const float*)d_in[6];
    const float* w_l1  = (const float*)d_in[7];
    const float* b_l1  = (const float*)d_in[8];
    const float* w_r1  = (const float*)d_in[9];
    const float* w_ih  = (const float*)d_in[10];
    // d_in[11] = w_hh: dead (h0 = 0)
    const float* b_ih  = (const float*)d_in[12];
    const float* b_hh  = (const float*)d_in[13];
    const float* wc0   = (const float*)d_in[14];
    const float* bc0   = (const float*)d_in[15];
    const float* wc1   = (const float*)d_in[16];
    const float* bc1   = (const float*)d_in[17];
    const float* wc2   = (const float*)d_in[18];
    const float* bc2   = (const float*)d_in[19];

    const int N = in_sizes[0] / 128;
    const int E = in_sizes[1] / 2;
    const int B = in_sizes[2];

    char* ws = (char*)d_ws;
    size_t off = 0;
    auto alloc = [&](size_t bytes) -> void* {
        void* p = ws + off; off += (bytes + 255) & ~(size_t)255; return p;
    };
    float* arenaA   = (float*)alloc((size_t)N*128*4);   // mean0 -> mean1 -> gates
    float* arenaB   = (float*)alloc((size_t)N*128*4);   // h -> lstm/z0/z1
    float* ue       = (float*)alloc((size_t)B*128*4);
    int*   degi     = (int*)  alloc((size_t)N*4);
    int*   cursor   = (int*)  alloc((size_t)N*4);
    int*   flag     = (int*)  alloc((size_t)N*4);
    int*   row_start= (int*)  alloc((size_t)(N+1)*4);
    int*   chunksum = (int*)  alloc(1024*4);
    int*   col_idx  = (int*)  alloc((size_t)E*4);
    int*   ulist    = (int*)  alloc((size_t)B*4);
    int*   ucnt     = (int*)  alloc(256);
    float* wt0      = (float*)alloc(256*128*4);
    float* wt1      = (float*)alloc(256*128*4);
    float* wtg      = (float*)alloc(256*384*4);
    float* bsum     = (float*)alloc(384*4);
    float* ohtab    = (float*)alloc(5*384*4);
    float* wtc0     = (float*)alloc(256*128*4);
    float* wtc1     = (float*)alloc(128*64*4);

    float* mean0 = arenaA;
    float* h     = arenaB;
    float* mean1 = arenaA;                       // mean0 consumed by gemm<0> before this
    float* gates = arenaA;                       // mean1 consumed by gemm<1> before this
    float* lstm  = arenaB;                       // h consumed by gemm<1> before this
    float* z0    = arenaB + (size_t)B*128;
    float* z1    = arenaB + (size_t)B*128*2;

    hipMemsetAsync(degi,   0, (size_t)N*4, stream);
    hipMemsetAsync(cursor, 0, (size_t)N*4, stream);
    hipMemsetAsync(flag,   0, (size_t)N*4, stream);
    hipMemsetAsync(ucnt,   0, 256, stream);

    const int gE = (E + 255)/256;
    const int nchunk = (N + SCAN_CHUNK - 1)/SCAN_CHUNK;

    count_deg<<<gE, 256, 0, stream>>>(edge + E, E, degi);
    scan1<<<nchunk, 256, 0, stream>>>(degi, N, row_start, chunksum);
    scan2<<<1, 256, 0, stream>>>(chunksum, nchunk);
    scan3<<<(N + 255)/256, 256, 0, stream>>>(row_start, chunksum, N, E);
    fill_csr<<<gE, 256, 0, stream>>>(edge, edge + E, E, row_start, cursor, col_idx);
    flag_users<<<(B + 255)/256, 256, 0, stream>>>(uid, B, flag);
    compact_flags<<<(N + 255)/256, 256, 0, stream>>>(flag, N, ulist, ucnt);

    transpose_k<<<(128*128 + 255)/256, 256, 0, stream>>>(w_l0, wt0,            128, 128, 128);
    transpose_k<<<(128*128 + 255)/256, 256, 0, stream>>>(w_r0, wt0 + 128*128,  128, 128, 128);
    transpose_k<<<(128*128 + 255)/256, 256, 0, stream>>>(w_l1, wt1,            128, 128, 128);
    transpose_k<<<(128*128 + 255)/256, 256, 0, stream>>>(w_r1, wt1 + 128*128,  128, 128, 128);
    transpose_k<<<(128*256 + 255)/256, 256, 0, stream>>>(wc0,  wtc0,           128, 256, 128);
    transpose_k<<<( 64*128 + 255)/256, 256, 0, stream>>>(wc1,  wtc1,            64, 128,  64);
    prep_gates<<<(256*384 + 255)/256, 256, 0, stream>>>(w_ih, b_ih, b_hh, wtg, bsum, ohtab);

    // layer 0: mean over all nodes, then h = relu([mean0|x] @ [w_l0|w_r0]^T + b_l0)
    aggregate_k<<<(N + 3)/4, 256, 0, stream>>>(x, row_start, col_idx, nullptr, nullptr, mean0, N);
    GemmArgs gh { mean0, x, nullptr, wt0, 128, b_l0, nullptr, nullptr, h, 128, N };
    gemm_k<0><<<dim3((N + 63)/64, 1), THREADS, 0, stream>>>(gh);

    // layer 1: aggregation + dense only for user nodes (compacted list)
    aggregate_k<<<(B + 3)/4, 256, 0, stream>>>(h, row_start, col_idx, ulist, ucnt, mean1, N);
    GemmArgs gu { mean1, h, uid, wt1, 128, b_l1, nullptr, nullptr, ue, 128, B };
    gemm_k<1><<<dim3(B/64, 1), THREADS, 0, stream>>>(gu);

    // LSTM gates (i,g,o only) + activation
    GemmArgs gg { ue, x, uid, wtg, 384, bsum, ohtab, roles, gates, 384, B };
    gemm_k<2><<<dim3(B/64, 3), THREADS, 0, stream>>>(gg);
    lstm_act<<<(B*128 + 255)/256, 256, 0, stream>>>(gates, lstm, B);

    // classifier MLP
    GemmArgs gz0 { ue, lstm, nullptr, wtc0, 128, bc0, nullptr, nullptr, z0, 128, B };
    gemm_k<3><<<dim3(B/64, 1), THREADS, 0, stream>>>(gz0);
    GemmArgs gz1 { z0, nullptr, nullptr, wtc1, 64, bc1, nullptr, nullptr, z1, 64, B };
    gemm_k<4><<<dim3(B/64, 1), THREADS, 0, stream>>>(gz1);
    out_k<<<(B*8 + 255)/256, 256, 0, stream>>>(z1, wc2, bc2, (float*)d_out, B);

    (void)n_in; (void)out_size; (void)ws_size;
}

// Round 3
// 643.344 us; speedup vs baseline: 1.1619x; 1.0688x over previous
//
#include <hip/hip_runtime.h>
#include <hip/hip_fp16.h>
#include <math.h>

#define THREADS 256
#define KC 32

__device__ __forceinline__ float clipf(float v){ return fminf(fmaxf(v, -10.f), 10.f); }

// ---------------------------------------------------------------- CSR build
__global__ __launch_bounds__(256) void count_deg(const int* __restrict__ dstv, int E, int* __restrict__ deg){
    int i = blockIdx.x*256 + threadIdx.x;
    if (i < E) atomicAdd(&deg[dstv[i]], 1);
}

#define SCAN_CHUNK 1024
__global__ __launch_bounds__(256) void scan1(const int* __restrict__ deg, int N, int* __restrict__ row_start, int* __restrict__ chunksum){
    __shared__ int sh[256];
    int b = blockIdx.x, t = threadIdx.x;
    int base = b*SCAN_CHUNK + t*4;
    int d0 = (base+0 < N) ? deg[base+0] : 0;
    int d1 = (base+1 < N) ? deg[base+1] : 0;
    int d2 = (base+2 < N) ? deg[base+2] : 0;
    int d3 = (base+3 < N) ? deg[base+3] : 0;
    int ts = d0+d1+d2+d3;
    sh[t] = ts; __syncthreads();
    for (int off = 1; off < 256; off <<= 1){
        int v = (t >= off) ? sh[t-off] : 0;
        __syncthreads();
        sh[t] += v;
        __syncthreads();
    }
    int ex = sh[t] - ts;
    if (base+0 < N) row_start[base+0] = ex;
    if (base+1 < N) row_start[base+1] = ex + d0;
    if (base+2 < N) row_start[base+2] = ex + d0 + d1;
    if (base+3 < N) row_start[base+3] = ex + d0 + d1 + d2;
    if (t == 255) chunksum[b] = sh[255];
}

// valid for nb <= 256 (N=100000 -> nb=98)
__global__ __launch_bounds__(256) void scan2(int* __restrict__ chunksum, int nb){
    __shared__ int sh[256];
    int t = threadIdx.x;
    int v = (t < nb) ? chunksum[t] : 0;
    sh[t] = v; __syncthreads();
    for (int off = 1; off < 256; off <<= 1){
        int u = (t >= off) ? sh[t-off] : 0;
        __syncthreads();
        sh[t] += u;
        __syncthreads();
    }
    if (t < nb) chunksum[t] = sh[t] - v;   // exclusive
}

__global__ __launch_bounds__(256) void scan3(int* __restrict__ row_start, const int* __restrict__ chunksum, int N, int E){
    int i = blockIdx.x*256 + threadIdx.x;
    if (i < N) row_start[i] += chunksum[i >> 10];
    if (i == 0) row_start[N] = E;
}

__global__ __launch_bounds__(256) void fill_csr(const int* __restrict__ srcv, const int* __restrict__ dstv, int E,
                                                const int* __restrict__ row_start, int* __restrict__ cursor, int* __restrict__ col_idx){
    int i = blockIdx.x*256 + threadIdx.x;
    if (i < E){
        int d = dstv[i];
        int pos = atomicAdd(&cursor[d], 1);
        col_idx[row_start[d] + pos] = srcv[i];
    }
}

__global__ __launch_bounds__(256) void flag_users(const int* __restrict__ uid, int B, int* __restrict__ flag){
    int i = blockIdx.x*256 + threadIdx.x;
    if (i < B) flag[uid[i]] = 1;
}

__global__ __launch_bounds__(256) void compact_flags(const int* __restrict__ flag, int N, int* __restrict__ list, int* __restrict__ cnt){
    int i = blockIdx.x*256 + threadIdx.x;
    if (i < N && flag[i]){ int p = atomicAdd(cnt, 1); list[p] = i; }
}

// ---------------------------------------------------------------- x -> fp16 copy (for layer-0 gather)
__global__ __launch_bounds__(256) void convert_fp16(const float* __restrict__ in, __half* __restrict__ out, long n8){
    long t = (long)blockIdx.x*256 + threadIdx.x;
    if (t >= n8) return;
    long i = t*8;
    float4 a = *(const float4*)(in + i);
    float4 b = *(const float4*)(in + i + 4);
    union { __half2 h[4]; float4 f; } u;
    u.h[0] = __floats2half2_rn(a.x, a.y);
    u.h[1] = __floats2half2_rn(a.z, a.w);
    u.h[2] = __floats2half2_rn(b.x, b.y);
    u.h[3] = __floats2half2_rn(b.z, b.w);
    *(float4*)(out + i) = u.f;
}

// ---------------------------------------------------------------- layer-0 mean aggregation (fp16 gather, fp32 accum)
// one wave per node; 4 edge-groups of 16 lanes; each lane loads 16 B (8 halfs) of a 256 B row;
// 4 edge-steps unrolled => 4 independent gathers in flight per lane (16 edges per wave-iter).
__device__ __forceinline__ void accumh(float4& a0, float4& a1, float4 v){
    const __half2* h = (const __half2*)&v;
    float2 f0 = __half22float2(h[0]);
    float2 f1 = __half22float2(h[1]);
    float2 f2 = __half22float2(h[2]);
    float2 f3 = __half22float2(h[3]);
    a0.x += f0.x; a0.y += f0.y; a0.z += f1.x; a0.w += f1.y;
    a1.x += f2.x; a1.y += f2.y; a1.z += f3.x; a1.w += f3.y;
}

__global__ __launch_bounds__(256) void aggregate_h16(const __half* __restrict__ feat, const int* __restrict__ row_start,
                                                     const int* __restrict__ col_idx,
                                                     float* __restrict__ outmean, int N){
    int wave = (blockIdx.x*256 + threadIdx.x) >> 6;
    if (wave >= N) return;
    int lane = threadIdx.x & 63;
    int g  = lane >> 4;      // edge group 0..3
    int sl = lane & 15;      // float4 slot within the 256 B fp16 row
    int s = row_start[wave], e = row_start[wave+1];
    const float4* f16 = (const float4*)feat;     // 16 float4 per row
    float4 a0 = make_float4(0.f,0.f,0.f,0.f);
    float4 a1 = make_float4(0.f,0.f,0.f,0.f);
    int i = s + g;
    for (; i + 12 < e; i += 16){
        int s0 = col_idx[i];
        int s1 = col_idx[i+4];
        int s2 = col_idx[i+8];
        int s3 = col_idx[i+12];
        float4 v0 = f16[(long)s0*16 + sl];
        float4 v1 = f16[(long)s1*16 + sl];
        float4 v2 = f16[(long)s2*16 + sl];
        float4 v3 = f16[(long)s3*16 + sl];
        accumh(a0, a1, v0);
        accumh(a0, a1, v1);
        accumh(a0, a1, v2);
        accumh(a0, a1, v3);
    }
    for (; i < e; i += 4){
        float4 v0 = f16[(long)col_idx[i]*16 + sl];
        accumh(a0, a1, v0);
    }
    // reduce across the 4 edge groups
    a0.x += __shfl_xor(a0.x, 16, 64); a0.x += __shfl_xor(a0.x, 32, 64);
    a0.y += __shfl_xor(a0.y, 16, 64); a0.y += __shfl_xor(a0.y, 32, 64);
    a0.z += __shfl_xor(a0.z, 16, 64); a0.z += __shfl_xor(a0.z, 32, 64);
    a0.w += __shfl_xor(a0.w, 16, 64); a0.w += __shfl_xor(a0.w, 32, 64);
    a1.x += __shfl_xor(a1.x, 16, 64); a1.x += __shfl_xor(a1.x, 32, 64);
    a1.y += __shfl_xor(a1.y, 16, 64); a1.y += __shfl_xor(a1.y, 32, 64);
    a1.z += __shfl_xor(a1.z, 16, 64); a1.z += __shfl_xor(a1.z, 32, 64);
    a1.w += __shfl_xor(a1.w, 16, 64); a1.w += __shfl_xor(a1.w, 32, 64);
    if (g == 0){
        float inv = 1.f / fmaxf((float)(e - s), 1.f);
        a0.x *= inv; a0.y *= inv; a0.z *= inv; a0.w *= inv;
        a1.x *= inv; a1.y *= inv; a1.z *= inv; a1.w *= inv;
        float4* om = (float4*)(outmean + (long)wave*128 + sl*8);
        om[0] = a0;
        om[1] = a1;
    }
}

// ---------------------------------------------------------------- layer-1 mean aggregation (fp32 gather, compacted list)
__global__ __launch_bounds__(256) void aggregate_k(const float* __restrict__ feat, const int* __restrict__ row_start,
                                                   const int* __restrict__ col_idx,
                                                   const int* __restrict__ list, const int* __restrict__ cnt,
                                                   float* __restrict__ outmean, int N){
    int wave = (blockIdx.x*256 + threadIdx.x) >> 6;
    int lane = threadIdx.x & 63;
    if (wave >= *cnt) return;
    int node = list[wave];
    int s = row_start[node], e = row_start[node+1];
    int half = lane >> 5;       // 0/1: alternate edges
    int sl   = lane & 31;       // float4 slot within the 128-float row
    const float4* feat4 = (const float4*)feat;
    float4 a0 = make_float4(0.f,0.f,0.f,0.f);
    float4 a1 = make_float4(0.f,0.f,0.f,0.f);
    int i = s + half;
    for (; i + 6 < e; i += 8){
        int s0 = col_idx[i];
        int s1 = col_idx[i+2];
        int s2 = col_idx[i+4];
        int s3 = col_idx[i+6];
        float4 v0 = feat4[(long)s0*32 + sl];
        float4 v1 = feat4[(long)s1*32 + sl];
        float4 v2 = feat4[(long)s2*32 + sl];
        float4 v3 = feat4[(long)s3*32 + sl];
        a0.x += v0.x + v1.x; a0.y += v0.y + v1.y; a0.z += v0.z + v1.z; a0.w += v0.w + v1.w;
        a1.x += v2.x + v3.x; a1.y += v2.y + v3.y; a1.z += v2.z + v3.z; a1.w += v2.w + v3.w;
    }
    for (; i < e; i += 2){
        int s0 = col_idx[i];
        float4 v0 = feat4[(long)s0*32 + sl];
        a0.x += v0.x; a0.y += v0.y; a0.z += v0.z; a0.w += v0.w;
    }
    a0.x += a1.x; a0.y += a1.y; a0.z += a1.z; a0.w += a1.w;
    a0.x += __shfl_xor(a0.x, 32, 64);
    a0.y += __shfl_xor(a0.y, 32, 64);
    a0.z += __shfl_xor(a0.z, 32, 64);
    a0.w += __shfl_xor(a0.w, 32, 64);
    if (half == 0){
        float inv = 1.f / fmaxf((float)(e - s), 1.f);
        a0.x *= inv; a0.y *= inv; a0.z *= inv; a0.w *= inv;
        ((float4*)outmean)[(long)node*32 + sl] = a0;
    }
}

// ---------------------------------------------------------------- weight prep
__global__ __launch_bounds__(256) void transpose_k(const float* __restrict__ in, float* __restrict__ out, int R, int K, int outN){
    int idx = blockIdx.x*256 + threadIdx.x;
    if (idx >= R*K) return;
    int j = idx / K, k = idx % K;
    out[k*outN + j] = in[j*K + k];
}

// gates weights: jj in [0,384) maps to w_ih row j (i:0-127, g:256-383, o:384-511); f-gate dead (c0=0).
__global__ __launch_bounds__(256) void prep_gates(const float* __restrict__ w_ih, const float* __restrict__ b_ih, const float* __restrict__ b_hh,
                                                  float* __restrict__ wtg, float* __restrict__ bsum, float* __restrict__ ohtab){
    int idx = blockIdx.x*256 + threadIdx.x;
    if (idx < 256*384){
        int jj = idx % 384, k = idx / 384;
        int j = jj + ((jj >= 128) ? 128 : 0);
        wtg[k*384 + jj] = w_ih[j*261 + k];
    }
    if (idx < 384){
        int jj = idx; int j = jj + ((jj >= 128) ? 128 : 0);
        bsum[jj] = b_ih[j] + b_hh[j];
        for (int r = 0; r < 5; ++r) ohtab[r*384 + jj] = w_ih[j*261 + 256 + r];
    }
}

// ---------------------------------------------------------------- generic fp32 GEMM
// MODE 0: h    = relu([mean0|x]      @ wt0 + b_l0)            M=N rows
// MODE 1: ue   = clip([mean1|h][uid] @ wt1 + b_l1)            M=B rows (gathered)
// MODE 2: gates=      [ue|clip(x[uid])] @ wtg + bsum + onehot M=B rows
// MODE 3: z0   = relu([ue|lstm]      @ wtc0 + bc0)
// MODE 4: z1   = relu(z0             @ wtc1 + bc1)  (K=128, BN=64)
struct GemmArgs {
    const float* a0; const float* a1; const int* g;
    const float* wt; int ncolsW;
    const float* bias; const float* ohtab; const int* roles;
    float* out; int ncolsOut; int M;
};

template<int MODE>
__device__ __forceinline__ float4 load_a(const GemmArgs& A, int row, int k){
    if constexpr (MODE == 1){
        int node = A.g[row];
        const float* p = (k < 128) ? A.a0 + (long)node*128 + k : A.a1 + (long)node*128 + (k-128);
        return *(const float4*)p;
    } else if constexpr (MODE == 2){
        if (k < 128) return *(const float4*)(A.a0 + (long)row*128 + k);
        int node = A.g[row];
        float4 v = *(const float4*)(A.a1 + (long)node*128 + (k-128));
        v.x = clipf(v.x); v.y = clipf(v.y); v.z = clipf(v.z); v.w = clipf(v.w);
        return v;
    } else if constexpr (MODE == 4){
        return *(const float4*)(A.a0 + (long)row*128 + k);
    } else {
        const float* p = (k < 128) ? A.a0 + (long)row*128 + k : A.a1 + (long)row*128 + (k-128);
        return *(const float4*)p;
    }
}

template<int MODE>
__global__ __launch_bounds__(THREADS) void gemm_k(GemmArgs A){
    constexpr int BM = 64;
    constexpr int BN = (MODE == 4) ? 64 : 128;
    constexpr int TN = 4;
    constexpr int CT = BN / TN;          // col-threads: 32 or 16
    constexpr int RT = THREADS / CT;     // row-threads: 8 or 16
    constexpr int TM = BM / RT;          // 8 or 4
    constexpr int KTOT = (MODE == 4) ? 128 : 256;
    constexpr int AST = BM + 4;          // 68: rows stay 16B-aligned (68*4 = 272 = 17*16)

    // k-major A tile: inner-loop A reads become broadcast ds_read_b128
    __shared__ __align__(16) float As[KC][AST];
    __shared__ __align__(16) float Ws[KC][BN];

    const int tid  = threadIdx.x;
    const int row0 = blockIdx.x * BM;
    const int col0 = blockIdx.y * BN;
    const int c  = tid % CT;
    const int rt = tid / CT;

    float acc[TM][TN];
    #pragma unroll
    for (int i = 0; i < TM; ++i)
        #pragma unroll
        for (int j = 0; j < TN; ++j) acc[i][j] = 0.f;

    for (int ko = 0; ko < KTOT; ko += KC){
        #pragma unroll
        for (int it = 0; it < (BM*KC/4)/THREADS; ++it){      // 2 iters
            int idx = it*THREADS + tid;
            int r  = idx >> 3;         // KC/4 = 8 float4 per row
            int k4 = idx & 7;
            int grow = row0 + r; if (grow >= A.M) grow = A.M - 1;
            float4 v = load_a<MODE>(A, grow, ko + k4*4);
            As[k4*4+0][r] = v.x;
            As[k4*4+1][r] = v.y;
            As[k4*4+2][r] = v.z;
            As[k4*4+3][r] = v.w;
        }
        #pragma unroll
        for (int it = 0; it < (KC*BN/4)/THREADS; ++it){      // 4 (BN=128) or 2 (BN=64)
            int idx = it*THREADS + tid;
            int kk = idx / (BN/4);
            int c4 = idx % (BN/4);
            float4 v = *(const float4*)&A.wt[(long)(ko+kk)*A.ncolsW + col0 + c4*4];
            *(float4*)&Ws[kk][c4*4] = v;
        }
        __syncthreads();
        #pragma unroll
        for (int kk = 0; kk < KC; ++kk){
            float4 wv = *(const float4*)&Ws[kk][c*4];
            float w[TN] = {wv.x, wv.y, wv.z, wv.w};
            float a[TM];
            #pragma unroll
            for (int q = 0; q < TM/4; ++q){
                float4 av = *(const float4*)&As[kk][rt*TM + q*4];
                a[q*4+0] = av.x; a[q*4+1] = av.y; a[q*4+2] = av.z; a[q*4+3] = av.w;
            }
            #pragma unroll
            for (int i = 0; i < TM; ++i)
                #pragma unroll
                for (int j = 0; j < TN; ++j) acc[i][j] = fmaf(a[i], w[j], acc[i][j]);
        }
        __syncthreads();
    }

    #pragma unroll
    for (int i = 0; i < TM; ++i){
        int grow = row0 + rt*TM + i;
        if (grow >= A.M) continue;
        #pragma unroll
        for (int j = 0; j < TN; ++j){
            int gcol = col0 + c*4 + j;
            float v = acc[i][j];
            if constexpr (MODE == 0)      v = fmaxf(v + A.bias[gcol], 0.f);
            else if constexpr (MODE == 1) v = clipf(v + A.bias[gcol]);
            else if constexpr (MODE == 2) v = v + A.bias[gcol] + A.ohtab[A.roles[grow]*384 + gcol];
            else                          v = fmaxf(v + A.bias[gcol], 0.f);
            A.out[(long)grow*A.ncolsOut + gcol] = v;
        }
    }
}

// ---------------------------------------------------------------- LSTM activation (f-gate dead, c0=0)
__global__ __launch_bounds__(256) void lstm_act(const float* __restrict__ gates, float* __restrict__ lstm, int B){
    int idx = blockIdx.x*256 + threadIdx.x;
    if (idx >= B*128) return;
    int b = idx >> 7, j = idx & 127;
    const float* gr = gates + (long)b*384;
    float i_ = gr[j], g_ = gr[128 + j], o_ = gr[256 + j];
    float si = 1.f/(1.f + expf(-i_));
    float c  = si * tanhf(g_);
    float so = 1.f/(1.f + expf(-o_));
    lstm[idx] = clipf(so * tanhf(c));
}

// ---------------------------------------------------------------- final tiny GEMM [B,64]@[64,5]
__global__ __launch_bounds__(256) void out_k(const float* __restrict__ z1, const float* __restrict__ wc2, const float* __restrict__ bc2,
                                             float* __restrict__ out, int B){
    int idx = blockIdx.x*256 + threadIdx.x;
    int b = idx >> 3, r = idx & 7;
    if (b >= B || r >= 5) return;
    const float* zr = z1 + (long)b*64;
    const float* wr = wc2 + r*64;
    float acc = bc2[r];
    #pragma unroll 16
    for (int k = 0; k < 64; ++k) acc = fmaf(zr[k], wr[k], acc);
    out[b*5 + r] = acc;
}

// ----------------------------------------------------------------
extern "C" void kernel_launch(void* const* d_in, const int* in_sizes, int n_in,
                              void* d_out, int out_size, void* d_ws, size_t ws_size,
                              hipStream_t stream){
    const float* x     = (const float*)d_in[0];
    const int*   edge  = (const int*)  d_in[1];
    const int*   uid   = (const int*)  d_in[2];
    const int*   roles = (const int*)  d_in[3];
    const float* w_l0  = (const float*)d_in[4];
    const float* b_l0  = (const float*)d_in[5];
    const float* w_r0  = (const float*)d_in[6];
    const float* w_l1  = (const float*)d_in[7];
    const float* b_l1  = (const float*)d_in[8];
    const float* w_r1  = (const float*)d_in[9];
    const float* w_ih  = (const float*)d_in[10];
    // d_in[11] = w_hh: dead (h0 = 0)
    const float* b_ih  = (const float*)d_in[12];
    const float* b_hh  = (const float*)d_in[13];
    const float* wc0   = (const float*)d_in[14];
    const float* bc0   = (const float*)d_in[15];
    const float* wc1   = (const float*)d_in[16];
    const float* bc1   = (const float*)d_in[17];
    const float* wc2   = (const float*)d_in[18];
    const float* bc2   = (const float*)d_in[19];

    const int N = in_sizes[0] / 128;
    const int E = in_sizes[1] / 2;
    const int B = in_sizes[2];

    char* ws = (char*)d_ws;
    size_t off = 0;
    auto alloc = [&](size_t bytes) -> void* {
        void* p = ws + off; off += (bytes + 255) & ~(size_t)255; return p;
    };
    float* arenaA   = (float*)alloc((size_t)N*128*4);   // mean0 -> mean1 -> gates
    float* arenaB   = (float*)alloc((size_t)N*128*4);   // h -> lstm/z0/z1
    float* ue       = (float*)alloc((size_t)B*128*4);
    __half* xh      = (__half*)alloc((size_t)N*128*2);
    int*   degi     = (int*)  alloc((size_t)N*4);
    int*   cursor   = (int*)  alloc((size_t)N*4);
    int*   flag     = (int*)  alloc((size_t)N*4);
    int*   row_start= (int*)  alloc((size_t)(N+1)*4);
    int*   chunksum = (int*)  alloc(1024*4);
    int*   col_idx  = (int*)  alloc((size_t)E*4);
    int*   ulist    = (int*)  alloc((size_t)B*4);
    int*   ucnt     = (int*)  alloc(256);
    float* wt0      = (float*)alloc(256*128*4);
    float* wt1      = (float*)alloc(256*128*4);
    float* wtg      = (float*)alloc(256*384*4);
    float* bsum     = (float*)alloc(384*4);
    float* ohtab    = (float*)alloc(5*384*4);
    float* wtc0     = (float*)alloc(256*128*4);
    float* wtc1     = (float*)alloc(128*64*4);

    float* mean0 = arenaA;
    float* h     = arenaB;
    float* mean1 = arenaA;                       // mean0 consumed by gemm<0> before this
    float* gates = arenaA;                       // mean1 consumed by gemm<1> before this
    float* lstm  = arenaB;                       // h consumed by gemm<1> before this
    float* z0    = arenaB + (size_t)B*128;
    float* z1    = arenaB + (size_t)B*128*2;

    hipMemsetAsync(degi,   0, (size_t)N*4, stream);
    hipMemsetAsync(cursor, 0, (size_t)N*4, stream);
    hipMemsetAsync(flag,   0, (size_t)N*4, stream);
    hipMemsetAsync(ucnt,   0, 256, stream);

    const int gE = (E + 255)/256;
    const int nchunk = (N + SCAN_CHUNK - 1)/SCAN_CHUNK;

    count_deg<<<gE, 256, 0, stream>>>(edge + E, E, degi);
    scan1<<<nchunk, 256, 0, stream>>>(degi, N, row_start, chunksum);
    scan2<<<1, 256, 0, stream>>>(chunksum, nchunk);
    scan3<<<(N + 255)/256, 256, 0, stream>>>(row_start, chunksum, N, E);
    fill_csr<<<gE, 256, 0, stream>>>(edge, edge + E, E, row_start, cursor, col_idx);
    flag_users<<<(B + 255)/256, 256, 0, stream>>>(uid, B, flag);
    compact_flags<<<(N + 255)/256, 256, 0, stream>>>(flag, N, ulist, ucnt);

    convert_fp16<<<(N*128/8 + 255)/256, 256, 0, stream>>>(x, xh, (long)N*128/8);

    transpose_k<<<(128*128 + 255)/256, 256, 0, stream>>>(w_l0, wt0,            128, 128, 128);
    transpose_k<<<(128*128 + 255)/256, 256, 0, stream>>>(w_r0, wt0 + 128*128,  128, 128, 128);
    transpose_k<<<(128*128 + 255)/256, 256, 0, stream>>>(w_l1, wt1,            128, 128, 128);
    transpose_k<<<(128*128 + 255)/256, 256, 0, stream>>>(w_r1, wt1 + 128*128,  128, 128, 128);
    transpose_k<<<(128*256 + 255)/256, 256, 0, stream>>>(wc0,  wtc0,           128, 256, 128);
    transpose_k<<<( 64*128 + 255)/256, 256, 0, stream>>>(wc1,  wtc1,            64, 128,  64);
    prep_gates<<<(256*384 + 255)/256, 256, 0, stream>>>(w_ih, b_ih, b_hh, wtg, bsum, ohtab);

    // layer 0: mean over all nodes (fp16 gather), then h = relu([mean0|x] @ [w_l0|w_r0]^T + b_l0)
    aggregate_h16<<<(N + 3)/4, 256, 0, stream>>>(xh, row_start, col_idx, mean0, N);
    GemmArgs gh { mean0, x, nullptr, wt0, 128, b_l0, nullptr, nullptr, h, 128, N };
    gemm_k<0><<<dim3((N + 63)/64, 1), THREADS, 0, stream>>>(gh);

    // layer 1: aggregation + dense only for user nodes (compacted list, fp32 gather)
    aggregate_k<<<(B + 3)/4, 256, 0, stream>>>(h, row_start, col_idx, ulist, ucnt, mean1, N);
    GemmArgs gu { mean1, h, uid, wt1, 128, b_l1, nullptr, nullptr, ue, 128, B };
    gemm_k<1><<<dim3(B/64, 1), THREADS, 0, stream>>>(gu);

    // LSTM gates (i,g,o only) + activation
    GemmArgs gg { ue, x, uid, wtg, 384, bsum, ohtab, roles, gates, 384, B };
    gemm_k<2><<<dim3(B/64, 3), THREADS, 0, stream>>>(gg);
    lstm_act<<<(B*128 + 255)/256, 256, 0, stream>>>(gates, lstm, B);

    // classifier MLP
    GemmArgs gz0 { ue, lstm, nullptr, wtc0, 128, bc0, nullptr, nullptr, z0, 128, B };
    gemm_k<3><<<dim3(B/64, 1), THREADS, 0, stream>>>(gz0);
    GemmArgs gz1 { z0, nullptr, nullptr, wtc1, 64, bc1, nullptr, nullptr, z1, 64, B };
    gemm_k<4><<<dim3(B/64, 1), THREADS, 0, stream>>>(gz1);
    out_k<<<(B*8 + 255)/256, 256, 0, stream>>>(z1, wc2, bc2, (float*)d_out, B);

    (void)n_in; (void)out_size; (void)ws_size;
}

// Round 4
// 605.401 us; speedup vs baseline: 1.2347x; 1.0627x over previous
//
#include <hip/hip_runtime.h>
#include <hip/hip_fp16.h>
#include <math.h>

#define THREADS 256
#define KC 32

__device__ __forceinline__ float clipf(float v){ return fminf(fmaxf(v, -10.f), 10.f); }

typedef __attribute__((ext_vector_type(8))) short bf16x8;
typedef __attribute__((ext_vector_type(4))) float f32x4;

// split fp32 into bf16 hi + bf16 lo (3-term split-GEMM decomposition)
__device__ __forceinline__ void split_bf16(float f, short& hi, short& lo){
    union { float f; unsigned u; } a; a.f = f;
    unsigned r = (a.u + 0x7FFFu + ((a.u >> 16) & 1u)) & 0xFFFF0000u;
    hi = (short)(r >> 16);
    union { unsigned u; float f; } b; b.u = r;
    float rem = f - b.f;                       // exactly representable
    union { float f; unsigned u; } c; c.f = rem;
    unsigned r2 = c.u + 0x7FFFu + ((c.u >> 16) & 1u);
    lo = (short)(r2 >> 16);
}

// ---------------------------------------------------------------- CSR build
__global__ __launch_bounds__(256) void count_deg(const int* __restrict__ dstv, int E, int* __restrict__ deg){
    int i = blockIdx.x*256 + threadIdx.x;
    if (i < E) atomicAdd(&deg[dstv[i]], 1);
}

#define SCAN_CHUNK 1024
__global__ __launch_bounds__(256) void scan1(const int* __restrict__ deg, int N, int* __restrict__ row_start, int* __restrict__ chunksum){
    __shared__ int sh[256];
    int b = blockIdx.x, t = threadIdx.x;
    int base = b*SCAN_CHUNK + t*4;
    int d0 = (base+0 < N) ? deg[base+0] : 0;
    int d1 = (base+1 < N) ? deg[base+1] : 0;
    int d2 = (base+2 < N) ? deg[base+2] : 0;
    int d3 = (base+3 < N) ? deg[base+3] : 0;
    int ts = d0+d1+d2+d3;
    sh[t] = ts; __syncthreads();
    for (int off = 1; off < 256; off <<= 1){
        int v = (t >= off) ? sh[t-off] : 0;
        __syncthreads();
        sh[t] += v;
        __syncthreads();
    }
    int ex = sh[t] - ts;
    if (base+0 < N) row_start[base+0] = ex;
    if (base+1 < N) row_start[base+1] = ex + d0;
    if (base+2 < N) row_start[base+2] = ex + d0 + d1;
    if (base+3 < N) row_start[base+3] = ex + d0 + d1 + d2;
    if (t == 255) chunksum[b] = sh[255];
}

// valid for nb <= 256 (N=100000 -> nb=98)
__global__ __launch_bounds__(256) void scan2(int* __restrict__ chunksum, int nb){
    __shared__ int sh[256];
    int t = threadIdx.x;
    int v = (t < nb) ? chunksum[t] : 0;
    sh[t] = v; __syncthreads();
    for (int off = 1; off < 256; off <<= 1){
        int u = (t >= off) ? sh[t-off] : 0;
        __syncthreads();
        sh[t] += u;
        __syncthreads();
    }
    if (t < nb) chunksum[t] = sh[t] - v;   // exclusive
}

__global__ __launch_bounds__(256) void scan3(int* __restrict__ row_start, const int* __restrict__ chunksum, int N, int E){
    int i = blockIdx.x*256 + threadIdx.x;
    if (i < N) row_start[i] += chunksum[i >> 10];
    if (i == 0) row_start[N] = E;
}

__global__ __launch_bounds__(256) void fill_csr(const int* __restrict__ srcv, const int* __restrict__ dstv, int E,
                                                const int* __restrict__ row_start, int* __restrict__ cursor, int* __restrict__ col_idx){
    int i = blockIdx.x*256 + threadIdx.x;
    if (i < E){
        int d = dstv[i];
        int pos = atomicAdd(&cursor[d], 1);
        col_idx[row_start[d] + pos] = srcv[i];
    }
}

__global__ __launch_bounds__(256) void flag_users(const int* __restrict__ uid, int B, int* __restrict__ flag){
    int i = blockIdx.x*256 + threadIdx.x;
    if (i < B) flag[uid[i]] = 1;
}

__global__ __launch_bounds__(256) void compact_flags(const int* __restrict__ flag, int N, int* __restrict__ list, int* __restrict__ cnt){
    int i = blockIdx.x*256 + threadIdx.x;
    if (i < N && flag[i]){ int p = atomicAdd(cnt, 1); list[p] = i; }
}

// ---------------------------------------------------------------- x -> fp16 copy (for layer-0 gather)
__global__ __launch_bounds__(256) void convert_fp16(const float* __restrict__ in, __half* __restrict__ out, long n8){
    long t = (long)blockIdx.x*256 + threadIdx.x;
    if (t >= n8) return;
    long i = t*8;
    float4 a = *(const float4*)(in + i);
    float4 b = *(const float4*)(in + i + 4);
    union { __half2 h[4]; float4 f; } u;
    u.h[0] = __floats2half2_rn(a.x, a.y);
    u.h[1] = __floats2half2_rn(a.z, a.w);
    u.h[2] = __floats2half2_rn(b.x, b.y);
    u.h[3] = __floats2half2_rn(b.z, b.w);
    *(float4*)(out + i) = u.f;
}

// ---------------------------------------------------------------- layer-0 mean aggregation (fp16 gather, fp32 accum)
__device__ __forceinline__ void accumh(float4& a0, float4& a1, float4 v){
    const __half2* h = (const __half2*)&v;
    float2 f0 = __half22float2(h[0]);
    float2 f1 = __half22float2(h[1]);
    float2 f2 = __half22float2(h[2]);
    float2 f3 = __half22float2(h[3]);
    a0.x += f0.x; a0.y += f0.y; a0.z += f1.x; a0.w += f1.y;
    a1.x += f2.x; a1.y += f2.y; a1.z += f3.x; a1.w += f3.y;
}

__global__ __launch_bounds__(256) void aggregate_h16(const __half* __restrict__ feat, const int* __restrict__ row_start,
                                                     const int* __restrict__ col_idx,
                                                     float* __restrict__ outmean, int N){
    int wave = (blockIdx.x*256 + threadIdx.x) >> 6;
    if (wave >= N) return;
    int lane = threadIdx.x & 63;
    int g  = lane >> 4;      // edge group 0..3
    int sl = lane & 15;      // float4 slot within the 256 B fp16 row
    int s = row_start[wave], e = row_start[wave+1];
    const float4* f16 = (const float4*)feat;     // 16 float4 per row
    float4 a0 = make_float4(0.f,0.f,0.f,0.f);
    float4 a1 = make_float4(0.f,0.f,0.f,0.f);
    int i = s + g;
    for (; i + 12 < e; i += 16){
        int s0 = col_idx[i];
        int s1 = col_idx[i+4];
        int s2 = col_idx[i+8];
        int s3 = col_idx[i+12];
        float4 v0 = f16[(long)s0*16 + sl];
        float4 v1 = f16[(long)s1*16 + sl];
        float4 v2 = f16[(long)s2*16 + sl];
        float4 v3 = f16[(long)s3*16 + sl];
        accumh(a0, a1, v0);
        accumh(a0, a1, v1);
        accumh(a0, a1, v2);
        accumh(a0, a1, v3);
    }
    for (; i < e; i += 4){
        float4 v0 = f16[(long)col_idx[i]*16 + sl];
        accumh(a0, a1, v0);
    }
    a0.x += __shfl_xor(a0.x, 16, 64); a0.x += __shfl_xor(a0.x, 32, 64);
    a0.y += __shfl_xor(a0.y, 16, 64); a0.y += __shfl_xor(a0.y, 32, 64);
    a0.z += __shfl_xor(a0.z, 16, 64); a0.z += __shfl_xor(a0.z, 32, 64);
    a0.w += __shfl_xor(a0.w, 16, 64); a0.w += __shfl_xor(a0.w, 32, 64);
    a1.x += __shfl_xor(a1.x, 16, 64); a1.x += __shfl_xor(a1.x, 32, 64);
    a1.y += __shfl_xor(a1.y, 16, 64); a1.y += __shfl_xor(a1.y, 32, 64);
    a1.z += __shfl_xor(a1.z, 16, 64); a1.z += __shfl_xor(a1.z, 32, 64);
    a1.w += __shfl_xor(a1.w, 16, 64); a1.w += __shfl_xor(a1.w, 32, 64);
    if (g == 0){
        float inv = 1.f / fmaxf((float)(e - s), 1.f);
        a0.x *= inv; a0.y *= inv; a0.z *= inv; a0.w *= inv;
        a1.x *= inv; a1.y *= inv; a1.z *= inv; a1.w *= inv;
        float4* om = (float4*)(outmean + (long)wave*128 + sl*8);
        om[0] = a0;
        om[1] = a1;
    }
}

// ---------------------------------------------------------------- layer-1 mean aggregation (fp32 gather, compacted list)
__global__ __launch_bounds__(256) void aggregate_k(const float* __restrict__ feat, const int* __restrict__ row_start,
                                                   const int* __restrict__ col_idx,
                                                   const int* __restrict__ list, const int* __restrict__ cnt,
                                                   float* __restrict__ outmean, int N){
    int wave = (blockIdx.x*256 + threadIdx.x) >> 6;
    int lane = threadIdx.x & 63;
    if (wave >= *cnt) return;
    int node = list[wave];
    int s = row_start[node], e = row_start[node+1];
    int half = lane >> 5;
    int sl   = lane & 31;
    const float4* feat4 = (const float4*)feat;
    float4 a0 = make_float4(0.f,0.f,0.f,0.f);
    float4 a1 = make_float4(0.f,0.f,0.f,0.f);
    int i = s + half;
    for (; i + 6 < e; i += 8){
        int s0 = col_idx[i];
        int s1 = col_idx[i+2];
        int s2 = col_idx[i+4];
        int s3 = col_idx[i+6];
        float4 v0 = feat4[(long)s0*32 + sl];
        float4 v1 = feat4[(long)s1*32 + sl];
        float4 v2 = feat4[(long)s2*32 + sl];
        float4 v3 = feat4[(long)s3*32 + sl];
        a0.x += v0.x + v1.x; a0.y += v0.y + v1.y; a0.z += v0.z + v1.z; a0.w += v0.w + v1.w;
        a1.x += v2.x + v3.x; a1.y += v2.y + v3.y; a1.z += v2.z + v3.z; a1.w += v2.w + v3.w;
    }
    for (; i < e; i += 2){
        int s0 = col_idx[i];
        float4 v0 = feat4[(long)s0*32 + sl];
        a0.x += v0.x; a0.y += v0.y; a0.z += v0.z; a0.w += v0.w;
    }
    a0.x += a1.x; a0.y += a1.y; a0.z += a1.z; a0.w += a1.w;
    a0.x += __shfl_xor(a0.x, 32, 64);
    a0.y += __shfl_xor(a0.y, 32, 64);
    a0.z += __shfl_xor(a0.z, 32, 64);
    a0.w += __shfl_xor(a0.w, 32, 64);
    if (half == 0){
        float inv = 1.f / fmaxf((float)(e - s), 1.f);
        a0.x *= inv; a0.y *= inv; a0.z *= inv; a0.w *= inv;
        ((float4*)outmean)[(long)node*32 + sl] = a0;
    }
}

// ---------------------------------------------------------------- weight prep
__global__ __launch_bounds__(256) void transpose_k(const float* __restrict__ in, float* __restrict__ out, int R, int K, int outN){
    int idx = blockIdx.x*256 + threadIdx.x;
    if (idx >= R*K) return;
    int j = idx / K, k = idx % K;
    out[k*outN + j] = in[j*K + k];
}

// wt0 split-bf16: [n=0..127][k=0..255], k<128 -> w_l0, k>=128 -> w_r0 (both already [out][in])
__global__ __launch_bounds__(256) void prep_wt0(const float* __restrict__ w_l0, const float* __restrict__ w_r0,
                                                short* __restrict__ wh, short* __restrict__ wl){
    int idx = blockIdx.x*256 + threadIdx.x;
    if (idx >= 128*256) return;
    int n = idx >> 8, k = idx & 255;
    float f = (k < 128) ? w_l0[n*128 + k] : w_r0[n*128 + (k - 128)];
    short h, l; split_bf16(f, h, l);
    wh[idx] = h; wl[idx] = l;
}

// gates weights: jj in [0,384) maps to w_ih row j (i:0-127, g:256-383, o:384-511); f-gate dead (c0=0).
__global__ __launch_bounds__(256) void prep_gates(const float* __restrict__ w_ih, const float* __restrict__ b_ih, const float* __restrict__ b_hh,
                                                  float* __restrict__ wtg, float* __restrict__ bsum, float* __restrict__ ohtab){
    int idx = blockIdx.x*256 + threadIdx.x;
    if (idx < 256*384){
        int jj = idx % 384, k = idx / 384;
        int j = jj + ((jj >= 128) ? 128 : 0);
        wtg[k*384 + jj] = w_ih[j*261 + k];
    }
    if (idx < 384){
        int jj = idx; int j = jj + ((jj >= 128) ? 128 : 0);
        bsum[jj] = b_ih[j] + b_hh[j];
        for (int r = 0; r < 5; ++r) ohtab[r*384 + jj] = w_ih[j*261 + 256 + r];
    }
}

// ---------------------------------------------------------------- MODE-0 GEMM via split-bf16 MFMA
// h = relu([mean0|x] @ wt0^T + b_l0), M=N rows, K=256, Ncols=128.
// 3-term split: C = Ah*Bh + Ah*Bl + Al*Bh  (error ~2^-17 per product)
#define AROW 40   // LDS row stride in bf16 (80 B: 16B-aligned, bank period 8 -> free 2-way)
__global__ __launch_bounds__(256) void gemm0_mfma(const float* __restrict__ mean0, const float* __restrict__ x,
                                                  const short* __restrict__ wh, const short* __restrict__ wl,
                                                  const float* __restrict__ bias, float* __restrict__ out, int M){
    __shared__ __align__(16) short Ah[64*AROW];
    __shared__ __align__(16) short Al[64*AROW];
    __shared__ __align__(16) short Wh[128*AROW];
    __shared__ __align__(16) short Wl[128*AROW];

    const int tid  = threadIdx.x;
    const int row0 = blockIdx.x * 64;
    const int wave = tid >> 6, lane = tid & 63;
    const int lm = lane & 15, quad = lane >> 4;

    f32x4 acc[8];
    #pragma unroll
    for (int t = 0; t < 8; ++t) acc[t] = (f32x4){0.f, 0.f, 0.f, 0.f};

    for (int ko = 0; ko < 256; ko += KC){
        const float* Asrc = (ko < 128) ? (mean0 + ko) : (x + (ko - 128));
        // stage A: 64 rows x 32 k fp32 -> bf16 hi/lo
        #pragma unroll
        for (int it = 0; it < 2; ++it){
            int idx = it*256 + tid;
            int r = idx >> 3, k4 = idx & 7;
            int grow = row0 + r; if (grow >= M) grow = M - 1;
            float4 v = *(const float4*)(Asrc + (long)grow*128 + k4*4);
            union { short s[4]; int2 p; } ph, pl;
            split_bf16(v.x, ph.s[0], pl.s[0]);
            split_bf16(v.y, ph.s[1], pl.s[1]);
            split_bf16(v.z, ph.s[2], pl.s[2]);
            split_bf16(v.w, ph.s[3], pl.s[3]);
            *(int2*)&Ah[r*AROW + k4*4] = ph.p;
            *(int2*)&Al[r*AROW + k4*4] = pl.p;
        }
        // stage W: 128 rows x 32 k bf16 (hi and lo)
        #pragma unroll
        for (int it = 0; it < 2; ++it){
            int idx = it*256 + tid;
            int n = idx >> 2, q = idx & 3;
            int4 vh = *(const int4*)(wh + (long)n*256 + ko + q*8);
            *(int4*)&Wh[n*AROW + q*8] = vh;
            int4 vlo = *(const int4*)(wl + (long)n*256 + ko + q*8);
            *(int4*)&Wl[n*AROW + q*8] = vlo;
        }
        __syncthreads();

        bf16x8 ah = *(const bf16x8*)&Ah[(wave*16 + lm)*AROW + quad*8];
        bf16x8 al = *(const bf16x8*)&Al[(wave*16 + lm)*AROW + quad*8];
        #pragma unroll
        for (int t = 0; t < 8; ++t){
            bf16x8 bh = *(const bf16x8*)&Wh[(t*16 + lm)*AROW + quad*8];
            bf16x8 bl = *(const bf16x8*)&Wl[(t*16 + lm)*AROW + quad*8];
            acc[t] = __builtin_amdgcn_mfma_f32_16x16x32_bf16(ah, bh, acc[t], 0, 0, 0);
            acc[t] = __builtin_amdgcn_mfma_f32_16x16x32_bf16(ah, bl, acc[t], 0, 0, 0);
            acc[t] = __builtin_amdgcn_mfma_f32_16x16x32_bf16(al, bh, acc[t], 0, 0, 0);
        }
        __syncthreads();
    }

    // epilogue: D row = quad*4+reg, col = lane&15 (per 16x16 tile)
    #pragma unroll
    for (int t = 0; t < 8; ++t){
        int col = t*16 + lm;
        float b = bias[col];
        #pragma unroll
        for (int r = 0; r < 4; ++r){
            int row = row0 + wave*16 + quad*4 + r;
            if (row < M) out[(long)row*128 + col] = fmaxf(acc[t][r] + b, 0.f);
        }
    }
}

// ---------------------------------------------------------------- generic fp32 GEMM (modes 1-4)
struct GemmArgs {
    const float* a0; const float* a1; const int* g;
    const float* wt; int ncolsW;
    const float* bias; const float* ohtab; const int* roles;
    float* out; int ncolsOut; int M;
};

template<int MODE>
__device__ __forceinline__ float4 load_a(const GemmArgs& A, int row, int k){
    if constexpr (MODE == 1){
        int node = A.g[row];
        const float* p = (k < 128) ? A.a0 + (long)node*128 + k : A.a1 + (long)node*128 + (k-128);
        return *(const float4*)p;
    } else if constexpr (MODE == 2){
        if (k < 128) return *(const float4*)(A.a0 + (long)row*128 + k);
        int node = A.g[row];
        float4 v = *(const float4*)(A.a1 + (long)node*128 + (k-128));
        v.x = clipf(v.x); v.y = clipf(v.y); v.z = clipf(v.z); v.w = clipf(v.w);
        return v;
    } else if constexpr (MODE == 4){
        return *(const float4*)(A.a0 + (long)row*128 + k);
    } else {
        const float* p = (k < 128) ? A.a0 + (long)row*128 + k : A.a1 + (long)row*128 + (k-128);
        return *(const float4*)p;
    }
}

template<int MODE>
__global__ __launch_bounds__(THREADS) void gemm_k(GemmArgs A){
    constexpr int BM = 64;
    constexpr int BN = (MODE == 4) ? 64 : 128;
    constexpr int TN = 4;
    constexpr int CT = BN / TN;
    constexpr int RT = THREADS / CT;
    constexpr int TM = BM / RT;
    constexpr int KTOT = (MODE == 4) ? 128 : 256;
    constexpr int AST = BM + 4;

    __shared__ __align__(16) float As[KC][AST];
    __shared__ __align__(16) float Ws[KC][BN];

    const int tid  = threadIdx.x;
    const int row0 = blockIdx.x * BM;
    const int col0 = blockIdx.y * BN;
    const int c  = tid % CT;
    const int rt = tid / CT;

    float acc[TM][TN];
    #pragma unroll
    for (int i = 0; i < TM; ++i)
        #pragma unroll
        for (int j = 0; j < TN; ++j) acc[i][j] = 0.f;

    for (int ko = 0; ko < KTOT; ko += KC){
        #pragma unroll
        for (int it = 0; it < (BM*KC/4)/THREADS; ++it){
            int idx = it*THREADS + tid;
            int r  = idx >> 3;
            int k4 = idx & 7;
            int grow = row0 + r; if (grow >= A.M) grow = A.M - 1;
            float4 v = load_a<MODE>(A, grow, ko + k4*4);
            As[k4*4+0][r] = v.x;
            As[k4*4+1][r] = v.y;
            As[k4*4+2][r] = v.z;
            As[k4*4+3][r] = v.w;
        }
        #pragma unroll
        for (int it = 0; it < (KC*BN/4)/THREADS; ++it){
            int idx = it*THREADS + tid;
            int kk = idx / (BN/4);
            int c4 = idx % (BN/4);
            float4 v = *(const float4*)&A.wt[(long)(ko+kk)*A.ncolsW + col0 + c4*4];
            *(float4*)&Ws[kk][c4*4] = v;
        }
        __syncthreads();
        #pragma unroll
        for (int kk = 0; kk < KC; ++kk){
            float4 wv = *(const float4*)&Ws[kk][c*4];
            float w[TN] = {wv.x, wv.y, wv.z, wv.w};
            float a[TM];
            #pragma unroll
            for (int q = 0; q < TM/4; ++q){
                float4 av = *(const float4*)&As[kk][rt*TM + q*4];
                a[q*4+0] = av.x; a[q*4+1] = av.y; a[q*4+2] = av.z; a[q*4+3] = av.w;
            }
            #pragma unroll
            for (int i = 0; i < TM; ++i)
                #pragma unroll
                for (int j = 0; j < TN; ++j) acc[i][j] = fmaf(a[i], w[j], acc[i][j]);
        }
        __syncthreads();
    }

    #pragma unroll
    for (int i = 0; i < TM; ++i){
        int grow = row0 + rt*TM + i;
        if (grow >= A.M) continue;
        #pragma unroll
        for (int j = 0; j < TN; ++j){
            int gcol = col0 + c*4 + j;
            float v = acc[i][j];
            if constexpr (MODE == 0)      v = fmaxf(v + A.bias[gcol], 0.f);
            else if constexpr (MODE == 1) v = clipf(v + A.bias[gcol]);
            else if constexpr (MODE == 2) v = v + A.bias[gcol] + A.ohtab[A.roles[grow]*384 + gcol];
            else                          v = fmaxf(v + A.bias[gcol], 0.f);
            A.out[(long)grow*A.ncolsOut + gcol] = v;
        }
    }
}

// ---------------------------------------------------------------- LSTM activation (f-gate dead, c0=0)
__global__ __launch_bounds__(256) void lstm_act(const float* __restrict__ gates, float* __restrict__ lstm, int B){
    int idx = blockIdx.x*256 + threadIdx.x;
    if (idx >= B*128) return;
    int b = idx >> 7, j = idx & 127;
    const float* gr = gates + (long)b*384;
    float i_ = gr[j], g_ = gr[128 + j], o_ = gr[256 + j];
    float si = 1.f/(1.f + expf(-i_));
    float c  = si * tanhf(g_);
    float so = 1.f/(1.f + expf(-o_));
    lstm[idx] = clipf(so * tanhf(c));
}

// ---------------------------------------------------------------- final tiny GEMM [B,64]@[64,5]
__global__ __launch_bounds__(256) void out_k(const float* __restrict__ z1, const float* __restrict__ wc2, const float* __restrict__ bc2,
                                             float* __restrict__ out, int B){
    int idx = blockIdx.x*256 + threadIdx.x;
    int b = idx >> 3, r = idx & 7;
    if (b >= B || r >= 5) return;
    const float* zr = z1 + (long)b*64;
    const float* wr = wc2 + r*64;
    float acc = bc2[r];
    #pragma unroll 16
    for (int k = 0; k < 64; ++k) acc = fmaf(zr[k], wr[k], acc);
    out[b*5 + r] = acc;
}

// ----------------------------------------------------------------
extern "C" void kernel_launch(void* const* d_in, const int* in_sizes, int n_in,
                              void* d_out, int out_size, void* d_ws, size_t ws_size,
                              hipStream_t stream){
    const float* x     = (const float*)d_in[0];
    const int*   edge  = (const int*)  d_in[1];
    const int*   uid   = (const int*)  d_in[2];
    const int*   roles = (const int*)  d_in[3];
    const float* w_l0  = (const float*)d_in[4];
    const float* b_l0  = (const float*)d_in[5];
    const float* w_r0  = (const float*)d_in[6];
    const float* w_l1  = (const float*)d_in[7];
    const float* b_l1  = (const float*)d_in[8];
    const float* w_r1  = (const float*)d_in[9];
    const float* w_ih  = (const float*)d_in[10];
    // d_in[11] = w_hh: dead (h0 = 0)
    const float* b_ih  = (const float*)d_in[12];
    const float* b_hh  = (const float*)d_in[13];
    const float* wc0   = (const float*)d_in[14];
    const float* bc0   = (const float*)d_in[15];
    const float* wc1   = (const float*)d_in[16];
    const float* bc1   = (const float*)d_in[17];
    const float* wc2   = (const float*)d_in[18];
    const float* bc2   = (const float*)d_in[19];

    const int N = in_sizes[0] / 128;
    const int E = in_sizes[1] / 2;
    const int B = in_sizes[2];

    char* ws = (char*)d_ws;
    size_t off = 0;
    auto alloc = [&](size_t bytes) -> void* {
        void* p = ws + off; off += (bytes + 255) & ~(size_t)255; return p;
    };
    float* arenaA   = (float*)alloc((size_t)N*128*4);   // mean0 -> mean1 -> gates
    float* arenaB   = (float*)alloc((size_t)N*128*4);   // h -> lstm/z0/z1
    float* ue       = (float*)alloc((size_t)B*128*4);
    __half* xh      = (__half*)alloc((size_t)N*128*2);
    int*   degi     = (int*)  alloc((size_t)N*4);
    int*   cursor   = (int*)  alloc((size_t)N*4);
    int*   flag     = (int*)  alloc((size_t)N*4);
    int*   row_start= (int*)  alloc((size_t)(N+1)*4);
    int*   chunksum = (int*)  alloc(1024*4);
    int*   col_idx  = (int*)  alloc((size_t)E*4);
    int*   ulist    = (int*)  alloc((size_t)B*4);
    int*   ucnt     = (int*)  alloc(256);
    short* wt0h     = (short*)alloc(128*256*2);
    short* wt0l     = (short*)alloc(128*256*2);
    float* wt1      = (float*)alloc(256*128*4);
    float* wtg      = (float*)alloc(256*384*4);
    float* bsum     = (float*)alloc(384*4);
    float* ohtab    = (float*)alloc(5*384*4);
    float* wtc0     = (float*)alloc(256*128*4);
    float* wtc1     = (float*)alloc(128*64*4);

    float* mean0 = arenaA;
    float* h     = arenaB;
    float* mean1 = arenaA;                       // mean0 consumed by gemm0 before this
    float* gates = arenaA;                       // mean1 consumed by gemm<1> before this
    float* lstm  = arenaB;                       // h consumed by gemm<1> before this
    float* z0    = arenaB + (size_t)B*128;
    float* z1    = arenaB + (size_t)B*128*2;

    hipMemsetAsync(degi,   0, (size_t)N*4, stream);
    hipMemsetAsync(cursor, 0, (size_t)N*4, stream);
    hipMemsetAsync(flag,   0, (size_t)N*4, stream);
    hipMemsetAsync(ucnt,   0, 256, stream);

    const int gE = (E + 255)/256;
    const int nchunk = (N + SCAN_CHUNK - 1)/SCAN_CHUNK;

    count_deg<<<gE, 256, 0, stream>>>(edge + E, E, degi);
    scan1<<<nchunk, 256, 0, stream>>>(degi, N, row_start, chunksum);
    scan2<<<1, 256, 0, stream>>>(chunksum, nchunk);
    scan3<<<(N + 255)/256, 256, 0, stream>>>(row_start, chunksum, N, E);
    fill_csr<<<gE, 256, 0, stream>>>(edge, edge + E, E, row_start, cursor, col_idx);
    flag_users<<<(B + 255)/256, 256, 0, stream>>>(uid, B, flag);
    compact_flags<<<(N + 255)/256, 256, 0, stream>>>(flag, N, ulist, ucnt);

    convert_fp16<<<(N*128/8 + 255)/256, 256, 0, stream>>>(x, xh, (long)N*128/8);

    prep_wt0<<<128, 256, 0, stream>>>(w_l0, w_r0, wt0h, wt0l);
    transpose_k<<<(128*128 + 255)/256, 256, 0, stream>>>(w_l1, wt1,            128, 128, 128);
    transpose_k<<<(128*128 + 255)/256, 256, 0, stream>>>(w_r1, wt1 + 128*128,  128, 128, 128);
    transpose_k<<<(128*256 + 255)/256, 256, 0, stream>>>(wc0,  wtc0,           128, 256, 128);
    transpose_k<<<( 64*128 + 255)/256, 256, 0, stream>>>(wc1,  wtc1,            64, 128,  64);
    prep_gates<<<(256*384 + 255)/256, 256, 0, stream>>>(w_ih, b_ih, b_hh, wtg, bsum, ohtab);

    // layer 0: mean over all nodes (fp16 gather), then h = relu([mean0|x] @ wt0^T + b_l0) via MFMA
    aggregate_h16<<<(N + 3)/4, 256, 0, stream>>>(xh, row_start, col_idx, mean0, N);
    gemm0_mfma<<<(N + 63)/64, 256, 0, stream>>>(mean0, x, wt0h, wt0l, b_l0, h, N);

    // layer 1: aggregation + dense only for user nodes (compacted list, fp32 gather)
    aggregate_k<<<(B + 3)/4, 256, 0, stream>>>(h, row_start, col_idx, ulist, ucnt, mean1, N);
    GemmArgs gu { mean1, h, uid, wt1, 128, b_l1, nullptr, nullptr, ue, 128, B };
    gemm_k<1><<<dim3(B/64, 1), THREADS, 0, stream>>>(gu);

    // LSTM gates (i,g,o only) + activation
    GemmArgs gg { ue, x, uid, wtg, 384, bsum, ohtab, roles, gates, 384, B };
    gemm_k<2><<<dim3(B/64, 3), THREADS, 0, stream>>>(gg);
    lstm_act<<<(B*128 + 255)/256, 256, 0, stream>>>(gates, lstm, B);

    // classifier MLP
    GemmArgs gz0 { ue, lstm, nullptr, wtc0, 128, bc0, nullptr, nullptr, z0, 128, B };
    gemm_k<3><<<dim3(B/64, 1), THREADS, 0, stream>>>(gz0);
    GemmArgs gz1 { z0, nullptr, nullptr, wtc1, 64, bc1, nullptr, nullptr, z1, 64, B };
    gemm_k<4><<<dim3(B/64, 1), THREADS, 0, stream>>>(gz1);
    out_k<<<(B*8 + 255)/256, 256, 0, stream>>>(z1, wc2, bc2, (float*)d_out, B);

    (void)n_in; (void)out_size; (void)ws_size;
}